// Round 12
// baseline (157.892 us; speedup 1.0000x reference)
//
#include <hip/hip_runtime.h>

#define WINDOW   512
#define STEPSZ   256
#define NFRAMES  127
#define NSAMP    32768
#define NBATCH   512
#define NFREQ    256

typedef __attribute__((ext_vector_type(8)))  short short8;   // 8 x bf16
typedef __attribute__((ext_vector_type(16))) float f32x16;   // 32x32 MFMA acc
typedef __attribute__((ext_vector_type(4)))  float f4;

static __device__ __forceinline__ short f2bf(float x) {
    union { float f; unsigned u; } v; v.f = x;
    unsigned r = (v.u + 0x7fffu + ((v.u >> 16) & 1u)) >> 16;
    return (short)r;
}

static __device__ __forceinline__ short8 cvt8(f4 a, f4 b) {
    short8 h;
#pragma unroll
    for (int q = 0; q < 4; ++q) { h[q] = f2bf(a[q]); h[q + 4] = f2bf(b[q]); }
    return h;
}

// ---- kernel 1: normalize basis -> bf16 32x32-fragment-major layout --------
// Bf[(ns*32 + ks)*64 + (n&31) + 32*kg2][8] holds B[n][k = ks*16 + kg2*8 + j]
// (real n -> ns 0..7, imag -> ns 8..15). Unchanged from R11 (proven).
__global__ __launch_bounds__(256) void prep_kernel(const float* __restrict__ br,
                                                   const float* __restrict__ bi,
                                                   short* __restrict__ Bf) {
    const int lane = threadIdx.x & 63;
    const int wid  = threadIdx.x >> 6;
    const int n    = blockIdx.x * 4 + wid;          // freq 0..255
    const float* pr = br + (size_t)n * WINDOW + lane * 8;
    const float* pi = bi + (size_t)n * WINDOW + lane * 8;
    f4 r0 = *(const f4*)pr;
    f4 r1 = *(const f4*)(pr + 4);
    f4 i0 = *(const f4*)pi;
    f4 i1 = *(const f4*)(pi + 4);
    float ss = 0.f;
#pragma unroll
    for (int j = 0; j < 4; ++j)
        ss += r0[j]*r0[j] + r1[j]*r1[j] + i0[j]*i0[j] + i1[j]*i1[j];
#pragma unroll
    for (int d = 1; d < 64; d <<= 1) ss += __shfl_xor(ss, d, 64);
    const float inv = 1.0f / (sqrtf(ss) + 1e-8f);
    short8 hr, hi;
#pragma unroll
    for (int j = 0; j < 4; ++j) {
        hr[j]     = f2bf(r0[j] * inv);
        hr[j + 4] = f2bf(r1[j] * inv);
        hi[j]     = f2bf(i0[j] * inv);
        hi[j + 4] = f2bf(i1[j] * inv);
    }
    const int ks  = lane >> 1, kg2 = lane & 1;
    const int nsR = n >> 5;
    const int nsI = 8 + (n >> 5);
    const int sl  = (n & 31) + 32 * kg2;
    *(short8*)(Bf + ((size_t)(nsR * 32 + ks) * 64 + sl) * 8) = hr;
    *(short8*)(Bf + ((size_t)(nsI * 32 + ks) * 64 + sl) * 8) = hi;
}

// ---- kernel 2: norms only (streams audio -> L3, writes invn + norms) ------
__global__ __launch_bounds__(512) void norms_kernel(const float* __restrict__ audio,
                                                    float* __restrict__ invn_g,
                                                    float* __restrict__ out_norms) {
    __shared__ float ps[128];
    const int tid = threadIdx.x;
    const int b   = blockIdx.x;
    const float* src = audio + (size_t)b * NSAMP;
#pragma unroll
    for (int it = 0; it < 8; ++it) {
        const int s = it * 4096 + tid * 8;
        f4 v0 = *(const f4*)(src + s);
        f4 v1 = *(const f4*)(src + s + 4);
        float ss = 0.f;
#pragma unroll
        for (int q = 0; q < 4; ++q) ss += v0[q]*v0[q] + v1[q]*v1[q];
        ss += __shfl_xor(ss, 1, 64);
        ss += __shfl_xor(ss, 2, 64);
        ss += __shfl_xor(ss, 4, 64);
        ss += __shfl_xor(ss, 8, 64);
        ss += __shfl_xor(ss, 16, 64);
        if ((tid & 31) == 0) ps[s >> 8] = ss;   // 16 chunk-partials per iter
    }
    __syncthreads();
    if (tid < NFRAMES) {
        const float nrm = sqrtf(ps[tid] + ps[tid + 1]);   // frame = chunks f,f+1
        out_norms[b * NFRAMES + tid] = nrm;
        invn_g[b * 128 + tid] = 1.0f / (nrm + 1e-8f);
    } else if (tid == 127) {
        invn_g[b * 128 + 127] = 0.0f;                     // pad row
    }
}

// ---- kernel 3: barrier-free MFMA GEMM --------------------------------------
// grid = 512 b * 4 q = 2048 blocks; 256 thr (4 waves). No LDS, no barriers:
// A-frags read from f32 audio (L3-hot after norms_kernel) + in-reg bf16 cvt;
// B-frags coalesced from Bf; even/odd depth-2 prefetch; waves free-run so
// stores/loads/MFMA of different waves overlap (no barrier drain anywhere).
#define LDA(dA0, dA1, dB0, dB1, ks)                       \
    dA0 = *(const f4*)(ap0 + (ks) * 16);                  \
    dA1 = *(const f4*)(ap0 + (ks) * 16 + 4);              \
    dB0 = *(const f4*)(ap1 + (ks) * 16);                  \
    dB1 = *(const f4*)(ap1 + (ks) * 16 + 4);
#define LDB(d0, d1, ks)                                   \
    d0 = *(const short8*)(bp0 + (size_t)(ks) * 512);      \
    d1 = *(const short8*)(bp1 + (size_t)(ks) * 512);

__global__ __launch_bounds__(256, 3) void gemm_kernel(const float* __restrict__ audio,
                                                      const short* __restrict__ Bf,
                                                      const float* __restrict__ invn_g,
                                                      float* __restrict__ out) {
    const int tid  = threadIdx.x;
    const int lane = tid & 63;
    const int wid  = tid >> 6;          // 0..3

    // XCD swizzle: the 4 blocks of one batch land on one XCD (A L2 reuse).
    const int lb = (blockIdx.x & 7) * 256 + (blockIdx.x >> 3);
    const int b  = lb >> 2;
    const int q  = lb & 3;
    const int mg = q & 1;               // row-half: rows [mg*64, mg*64+64)
    const int ng = (q >> 1) * 4 + wid;  // n-pair: nsups {2ng, 2ng+1}

    const int rl32 = lane & 31;
    const int kg2  = lane >> 5;

    float* out_real = out + 65024;
    float* out_imag = out + 65024 + 16646144;

    // A rows (clamp pad row 127 -> 126: C-row 127 is discarded at store)
    const int r0 = mg * 64 + rl32;
    int r1 = mg * 64 + 32 + rl32;
    if (r1 > 126) r1 = 126;
    const float* ap0 = audio + (size_t)b * NSAMP + r0 * 256 + kg2 * 8;
    const float* ap1 = audio + (size_t)b * NSAMP + r1 * 256 + kg2 * 8;

    const short* bp0 = Bf + ((size_t)(2 * ng + 0) * 32 * 64 + lane) * 8;
    const short* bp1 = Bf + ((size_t)(2 * ng + 1) * 32 * 64 + lane) * 8;

    // even/odd depth-2 prefetch buffers
    f4 e0A, e0B, e1A, e1B, o0A, o0B, o1A, o1B;
    short8 bE0, bE1, bO0, bO1;
    LDA(e0A, e0B, e1A, e1B, 0)
    LDB(bE0, bE1, 0)
    LDA(o0A, o0B, o1A, o1B, 1)
    LDB(bO0, bO1, 1)

    f32x16 acc[2][2];
    acc[0][0] = (f32x16)0.f; acc[0][1] = (f32x16)0.f;
    acc[1][0] = (f32x16)0.f; acc[1][1] = (f32x16)0.f;

#pragma unroll
    for (int ks = 0; ks < 32; ++ks) {
        short8 a0, a1, c0, c1;
        if ((ks & 1) == 0) {
            a0 = cvt8(e0A, e0B); a1 = cvt8(e1A, e1B);
            c0 = bE0; c1 = bE1;
            if (ks < 30) { LDA(e0A, e0B, e1A, e1B, ks + 2) LDB(bE0, bE1, ks + 2) }
        } else {
            a0 = cvt8(o0A, o0B); a1 = cvt8(o1A, o1B);
            c0 = bO0; c1 = bO1;
            if (ks < 30) { LDA(o0A, o0B, o1A, o1B, ks + 2) LDB(bO0, bO1, ks + 2) }
        }
        acc[0][0] = __builtin_amdgcn_mfma_f32_32x32x16_bf16(a0, c0, acc[0][0], 0, 0, 0);
        acc[1][0] = __builtin_amdgcn_mfma_f32_32x32x16_bf16(a1, c0, acc[1][0], 0, 0, 0);
        acc[0][1] = __builtin_amdgcn_mfma_f32_32x32x16_bf16(a0, c1, acc[0][1], 0, 0, 0);
        acc[1][1] = __builtin_amdgcn_mfma_f32_32x32x16_bf16(a1, c1, acc[1][1], 0, 0, 0);
    }

    // ---- Epilogue: C/D map col=lane&31, row=(reg&3)+8*(reg>>2)+4*(lane>>5) ----
#pragma unroll
    for (int mi = 0; mi < 2; ++mi) {
        const int rbase = mg * 64 + mi * 32 + 4 * kg2;
        float iv[16];
#pragma unroll
        for (int r = 0; r < 16; ++r)
            iv[r] = invn_g[b * 128 + rbase + (r & 3) + 8 * (r >> 2)];
#pragma unroll
        for (int s = 0; s < 2; ++s) {
            const int n = (2 * ng + s) * 32 + rl32;
            float* dst = (n < NFREQ) ? out_real : out_imag;
            const int kcol = n & (NFREQ - 1);
#pragma unroll
            for (int r = 0; r < 16; ++r) {
                const int fr = rbase + (r & 3) + 8 * (r >> 2);
                if (fr < NFRAMES)
                    dst[((size_t)b * NFRAMES + fr) * NFREQ + kcol] = acc[mi][s][r] * iv[r];
            }
        }
    }
}

extern "C" void kernel_launch(void* const* d_in, const int* in_sizes, int n_in,
                              void* d_out, int out_size, void* d_ws, size_t ws_size,
                              hipStream_t stream) {
    const float* audio = (const float*)d_in[0];
    const float* br    = (const float*)d_in[1];
    const float* bi    = (const float*)d_in[2];
    float* out = (float*)d_out;
    short* Bf     = (short*)d_ws;                          // 512 KiB
    float* invn_g = (float*)((char*)d_ws + (1 << 20));     // 256 KiB

    prep_kernel<<<64, 256, 0, stream>>>(br, bi, Bf);
    norms_kernel<<<NBATCH, 512, 0, stream>>>(audio, invn_g, out);
    gemm_kernel<<<NBATCH * 4, 256, 0, stream>>>(audio, Bf, invn_g, out);
}